// Round 25
// baseline (92.045 us; speedup 1.0000x reference)
//
#include <hip/hip_runtime.h>
#include <hip/hip_bf16.h>

#define BQ 4
#define SQ 4096
#define DQ 256
#define N3 768
#define KBLK 64
#define NITER (SQ / KBLK)
#define KHALF (NITER / 2)
#define LOG2E 1.44269504f
#define THR2 11.5415603f  // 8 * log2(e)

typedef __attribute__((ext_vector_type(8))) _Float16 f16x8;
typedef __attribute__((ext_vector_type(4))) _Float16 f16x4;
typedef __attribute__((ext_vector_type(4))) float f32x4;
typedef __attribute__((ext_vector_type(4))) unsigned int u32x4;

__device__ __forceinline__ short f2h(float f) {
  _Float16 h = (_Float16)f;
  union { _Float16 h; short s; } v; v.h = h;
  return v.s;
}

__device__ __forceinline__ void gload16(const void* g, void* lds) {
  __builtin_amdgcn_global_load_lds(
      (const __attribute__((address_space(1))) unsigned int*)g,
      (__attribute__((address_space(3))) unsigned int*)lds, 16, 0, 0);
}

// ---- prep: blocks 0..47 Wqkv->W16T; 48 = Wcomb; 49..304 x->x16 (fp16) -----
__global__ __launch_bounds__(256) void prep_kernel(
    const float* __restrict__ Wqkv, const float* __restrict__ Wproj,
    const float* __restrict__ bproj, const float* __restrict__ Wfc,
    const float* __restrict__ bfc, const float* __restrict__ x,
    short* __restrict__ W16T, float* __restrict__ Wc,
    short* __restrict__ x16) {
  const int t = threadIdx.x;
  if (blockIdx.x >= 49) {  // x -> fp16, coalesced
    const size_t base = (size_t)(blockIdx.x - 49) * 16384;
#pragma unroll 4
    for (int i = 0; i < 64; ++i)
      x16[base + i * 256 + t] = f2h(x[base + i * 256 + t]);
    return;
  }
  if (blockIdx.x == 48) {
    __shared__ float wf[256];
    wf[t] = Wfc[t];
    __syncthreads();
    float acc = 0.f;
    for (int j = 0; j < 256; ++j) acc += Wproj[(size_t)t * 256 + j] * wf[j];
    Wc[t] = acc;
    if (t == 0) {
      float c = bfc[0];
      for (int j = 0; j < 256; ++j) c += bproj[j] * wf[j];
      Wc[256] = c;
    }
    return;
  }
  __shared__ float tile[64][65];
  const int nb = (blockIdx.x % 12) * 64;
  const int kb = (blockIdx.x / 12) * 64;
  const int tr = t >> 6, tc = t & 63;
#pragma unroll
  for (int i = 0; i < 16; ++i)
    tile[tr + i * 4][tc] = Wqkv[(size_t)(kb + tr + i * 4) * N3 + nb + tc];
  __syncthreads();
#pragma unroll
  for (int i = 0; i < 16; ++i)
    W16T[(size_t)(nb + tr + i * 4) * 256 + kb + tc] = f2h(tile[tc][tr + i * 4]);
}

// ---- QKV GEMM: grid (128 m, 12 n), 512 thr, wave = 32x32 (2x2 frags) ------
// A[2][128][64] + B[2][64][64] fp16 LDS (48 KB -> 3 blocks/CU). 4 K-steps,
// single-barrier loop, XOR-swizzled gload16 staging. n-tiles 0..7 -> Q/K
// (K pre-scaled log2e); 8..11 -> u partials (summed by uvec_kernel).
__global__ __launch_bounds__(512, 3) void qkv_kernel(
    const short* __restrict__ x16, const short* __restrict__ W16T,
    const float* __restrict__ bqkv, const float* __restrict__ Wc,
    short* __restrict__ Qb, short* __restrict__ Kb,
    float* __restrict__ u_part) {
  __shared__ short As[2][128][64];
  __shared__ short Bs[2][64][64];
  __shared__ float u_red[4][2][2][16];  // [mq][nq][mf][row16]
  const int t = threadIdx.x;
  const int l = t & 63, w = t >> 6;
  const int lr = l & 15, lg = l >> 4;
  const int mq = w >> 1, nq = w & 1;
  const int Mbase = blockIdx.x * 128;
  const int bn = blockIdx.y;
  const int Nbase = bn * 64;

#define STAGE_AB(BUF, KS)                                                   \
  {                                                                         \
    _Pragma("unroll") for (int i = 0; i < 2; ++i) {                         \
      const int ar = w * 16 + i * 8 + (l >> 3);                             \
      const int gc = (l & 7) ^ (ar & 7);                                    \
      gload16(x16 + (size_t)(Mbase + ar) * 256 + (KS)*64 + gc * 8,          \
              &As[BUF][w * 16 + i * 8][0]);                                 \
    }                                                                       \
    {                                                                       \
      const int br = w * 8 + (l >> 3);                                      \
      const int gc = (l & 7) ^ (br & 7);                                    \
      gload16(W16T + (size_t)(Nbase + br) * 256 + (KS)*64 + gc * 8,         \
              &Bs[BUF][w * 8][0]);                                          \
    }                                                                       \
  }

  STAGE_AB(0, 0);

  // preload bias / Wc (keeps in-loop VM queue = staging only)
  float bias_v[2], wc_v[2] = {0.f, 0.f};
#pragma unroll
  for (int nf = 0; nf < 2; ++nf) {
    const int col = Nbase + nq * 32 + nf * 16 + lr;
    bias_v[nf] = bqkv[col];
    if (bn >= 8) wc_v[nf] = Wc[col - 512];
  }

  // XOR-swizzled fragment offsets (64-short rows, 8 chunks)
  int koff[2];
#pragma unroll
  for (int kk = 0; kk < 2; ++kk) koff[kk] = ((4 * kk + lg) ^ (lr & 7)) << 4;

  f32x4 acc[2][2] = {};

#pragma unroll
  for (int ks = 0; ks < 4; ++ks) {
    const int cur = ks & 1;
    asm volatile("s_waitcnt vmcnt(0)" ::: "memory");
    __builtin_amdgcn_s_barrier();
    __builtin_amdgcn_sched_barrier(0);
    if (ks < 3) STAGE_AB(cur ^ 1, ks + 1);  // flies over compute below

    const char* aR0 = (const char*)&As[cur][mq * 32 + lr][0];
    const char* aR1 = (const char*)&As[cur][mq * 32 + 16 + lr][0];
    const char* bR0 = (const char*)&Bs[cur][nq * 32 + lr][0];
    const char* bR1 = (const char*)&Bs[cur][nq * 32 + 16 + lr][0];
#pragma unroll
    for (int kk = 0; kk < 2; ++kk) {
      f16x8 a0 = *(const f16x8*)(aR0 + koff[kk]);
      f16x8 a1 = *(const f16x8*)(aR1 + koff[kk]);
      f16x8 b0 = *(const f16x8*)(bR0 + koff[kk]);
      f16x8 b1 = *(const f16x8*)(bR1 + koff[kk]);
      acc[0][0] = __builtin_amdgcn_mfma_f32_16x16x32_f16(a0, b0, acc[0][0], 0, 0, 0);
      acc[0][1] = __builtin_amdgcn_mfma_f32_16x16x32_f16(a0, b1, acc[0][1], 0, 0, 0);
      acc[1][0] = __builtin_amdgcn_mfma_f32_16x16x32_f16(a1, b0, acc[1][0], 0, 0, 0);
      acc[1][1] = __builtin_amdgcn_mfma_f32_16x16x32_f16(a1, b1, acc[1][1], 0, 0, 0);
    }
  }

  if (bn < 8) {
    const float sc = (bn < 4) ? 1.f : LOG2E;  // K pre-scaled for exp2
#pragma unroll
    for (int mf = 0; mf < 2; ++mf)
#pragma unroll
      for (int nf = 0; nf < 2; ++nf) {
        const int col = Nbase + nq * 32 + nf * 16 + lr;
#pragma unroll
        for (int r = 0; r < 4; ++r) {
          const int row = Mbase + mq * 32 + mf * 16 + lg * 4 + r;
          const short sv = f2h((acc[mf][nf][r] + bias_v[nf]) * sc);
          if (bn < 4) Qb[(size_t)row * DQ + col] = sv;
          else        Kb[(size_t)row * DQ + (col - 256)] = sv;
        }
      }
  } else {
    float up[2][4] = {};
#pragma unroll
    for (int nf = 0; nf < 2; ++nf)
#pragma unroll
      for (int mf = 0; mf < 2; ++mf)
#pragma unroll
        for (int r = 0; r < 4; ++r)
          up[mf][r] += (acc[mf][nf][r] + bias_v[nf]) * wc_v[nf];
#pragma unroll
    for (int mask = 1; mask <= 8; mask <<= 1)
#pragma unroll
      for (int mf = 0; mf < 2; ++mf)
#pragma unroll
        for (int r = 0; r < 4; ++r) up[mf][r] += __shfl_xor(up[mf][r], mask, 64);
    if (lr == 0) {
#pragma unroll
      for (int mf = 0; mf < 2; ++mf)
#pragma unroll
        for (int r = 0; r < 4; ++r)
          u_red[mq][nq][mf][lg * 4 + r] = up[mf][r];
    }
    __syncthreads();
    if (t < 128)
      u_part[(size_t)(bn - 8) * (BQ * SQ) + Mbase + t] =
          u_red[t >> 5][0][(t >> 4) & 1][t & 15] +
          u_red[t >> 5][1][(t >> 4) & 1][t & 15];
  }
#undef STAGE_AB
}

// ---- u16 = fp16( sum of 4 u partials ) ----
__global__ void uvec_kernel(const float* __restrict__ up,
                            short* __restrict__ u16) {
  const int i = blockIdx.x * 256 + threadIdx.x;
  u16[i] = f2h(up[i] + up[BQ * SQ + i] + up[2 * BQ * SQ + i] +
               up[3 * BQ * SQ + i]);
}

// --- Flash attention (r23 verbatim): 4 waves x (64q x 16k), MFMA num/den ---
__global__ __launch_bounds__(256, 2) void attn_kernel(
    const short* __restrict__ Qb, const short* __restrict__ Kb,
    const short* __restrict__ u16, float* __restrict__ Pm,
    float* __restrict__ Pd, float* __restrict__ Pn) {
  __shared__ short Ks[2][64][256];     // [buf][key][d], XOR-swizzled chunks
  __shared__ __align__(16) short u_lds[2048];  // fp16 u slice (4 KB)
  __shared__ float Mrg[4][64][3];      // [h][row]{m,den,num}

  const int t = threadIdx.x;
  const int l = t & 63, w = t >> 6;    // w = key-quarter h
  const int lr = l & 15, lg = l >> 4;
  const int bid = blockIdx.x;
  const int b = bid & 3;
  const int half = (bid >> 2) & 1;     // bid%8 -> XCD: one (b,half) per XCD
  const int qbase = (bid >> 3) * 64;

  const short* kbase = Kb + ((size_t)b * SQ + (size_t)half * (SQ / 2)) * DQ;
  const short* ubase = u16 + (size_t)b * SQ + half * (SQ / 2);

#define STAGE(BUF, KB)                                                      \
  {                                                                         \
    _Pragma("unroll") for (int i = 0; i < 8; ++i) {                         \
      const int kr = w * 16 + i * 2 + (l >> 5);                             \
      const int gc = (l & 31) ^ (kr & 7);                                   \
      gload16(kbase + (size_t)((KB)*64 + kr) * DQ + gc * 8,                 \
              &Ks[BUF][w * 16 + i * 2][0]);                                 \
    }                                                                       \
  }

  // ---- prologue: stage Q tile into Ks[0] (same XOR swizzle) + u slice ----
  {
    const short* qsrc = Qb + (size_t)(b * SQ + qbase) * DQ;
#pragma unroll
    for (int i = 0; i < 8; ++i) {
      const int qr = w * 16 + i * 2 + (l >> 5);
      const int gc = (l & 31) ^ (qr & 7);
      gload16(qsrc + (size_t)qr * DQ + gc * 8, &Ks[0][w * 16 + i * 2][0]);
    }
  }
  gload16(ubase + w * 512 + (l << 3), &u_lds[w * 512]);  // 2048 fp16 total

  // hoist loop-invariant XOR-swizzled fragment offsets
  int koff[8];
#pragma unroll
  for (int kk = 0; kk < 8; ++kk) koff[kk] = ((4 * kk + lg) ^ (lr & 7)) << 4;

  asm volatile("s_waitcnt vmcnt(0)" ::: "memory");
  __syncthreads();  // Q tile + u landed

  // Q fragments from LDS: q-row = mm*16+lr, all 64 q-rows per wave
  f16x8 qf[4][8];
#pragma unroll
  for (int mm = 0; mm < 4; ++mm) {
    const char* qR = (const char*)&Ks[0][mm * 16 + lr][0];
#pragma unroll
    for (int kk = 0; kk < 8; ++kk)
      qf[mm][kk] = *(const f16x8*)(qR + koff[kk]);
  }
  __syncthreads();  // all qf reads done before K staging clobbers Ks[0]

  float m_run[4] = {-1e30f, -1e30f, -1e30f, -1e30f};
  f32x4 numden[4] = {};  // per mm: reg0=num(row0), reg1=den(row1), rows>=2 zero

  STAGE(0, 0);  // first K tile

  for (int kb = 0; kb < KHALF; ++kb) {
    const int cur = kb & 1;
    asm volatile("s_waitcnt vmcnt(0)" ::: "memory");
    __builtin_amdgcn_s_barrier();
    __builtin_amdgcn_sched_barrier(0);
    if (kb + 1 < KHALF) STAGE(cur ^ 1, kb + 1);  // flies over compute below

    // S^T = K Q^T: wave's 16 keys x 64 q (4 independent 8-deep chains)
    const char* kR = (const char*)&Ks[cur][w * 16 + lr][0];
    f32x4 s[4] = {};
    __builtin_amdgcn_s_setprio(1);
#pragma unroll
    for (int kk = 0; kk < 8; ++kk) {
      f16x8 kf = *(const f16x8*)(kR + koff[kk]);
      s[0] = __builtin_amdgcn_mfma_f32_16x16x32_f16(kf, qf[0][kk], s[0], 0, 0, 0);
      s[1] = __builtin_amdgcn_mfma_f32_16x16x32_f16(kf, qf[1][kk], s[1], 0, 0, 0);
      s[2] = __builtin_amdgcn_mfma_f32_16x16x32_f16(kf, qf[2][kk], s[2], 0, 0, 0);
      s[3] = __builtin_amdgcn_mfma_f32_16x16x32_f16(kf, qf[3][kk], s[3], 0, 0, 0);
    }
    __builtin_amdgcn_s_setprio(0);

    // max-tree gate, defer-max online softmax (base 2)
    float mx[4];
#pragma unroll
    for (int mm = 0; mm < 4; ++mm)
      mx[mm] = fmaxf(fmaxf(s[mm][0], s[mm][1]), fmaxf(s[mm][2], s[mm][3]));
    const bool over = (mx[0] > m_run[0] + THR2) || (mx[1] > m_run[1] + THR2) ||
                      (mx[2] > m_run[2] + THR2) || (mx[3] > m_run[3] + THR2);
    if (__any(over)) {
#pragma unroll
      for (int mm = 0; mm < 4; ++mm) {
        float mt = mx[mm];
        mt = fmaxf(mt, __shfl_xor(mt, 16, 64));
        mt = fmaxf(mt, __shfl_xor(mt, 32, 64));
        const float mn = fmaxf(m_run[mm], mt);
        const float sc = __builtin_amdgcn_exp2f(m_run[mm] - mn);
        m_run[mm] = mn;
#pragma unroll
        for (int r = 0; r < 4; ++r) numden[mm][r] *= sc;
      }
    }

    // A operand: row0 = u (fp16), row1 = 1, rows 2..15 = 0
    f16x4 uf;
    {
      const f16x4 uraw = *(const f16x4*)&u_lds[kb * 64 + w * 16 + lg * 4];
#pragma unroll
      for (int j = 0; j < 4; ++j)
        uf[j] = (lr == 0) ? uraw[j]
                          : ((lr == 1) ? (_Float16)1.0f : (_Float16)0.0f);
    }

    // p = exp2(s - m) -> fp16 (pkrtz), accumulate num/den on MFMA pipe
#pragma unroll
    for (int mm = 0; mm < 4; ++mm) {
      const float p0 = __builtin_amdgcn_exp2f(s[mm][0] - m_run[mm]);
      const float p1 = __builtin_amdgcn_exp2f(s[mm][1] - m_run[mm]);
      const float p2 = __builtin_amdgcn_exp2f(s[mm][2] - m_run[mm]);
      const float p3 = __builtin_amdgcn_exp2f(s[mm][3] - m_run[mm]);
      const auto lo = __builtin_amdgcn_cvt_pkrtz(p0, p1);  // __fp16 x2
      const auto hi = __builtin_amdgcn_cvt_pkrtz(p2, p3);
      f16x4 pf;
      pf[0] = (_Float16)lo[0]; pf[1] = (_Float16)lo[1];
      pf[2] = (_Float16)hi[0]; pf[3] = (_Float16)hi[1];
      numden[mm] = __builtin_amdgcn_mfma_f32_16x16x16f16(uf, pf, numden[mm], 0, 0, 0);
    }
  }

  // num/den are complete per qrow in lanes lg==0 (reg0=num, reg1=den)
  if (lg == 0) {
#pragma unroll
    for (int mm = 0; mm < 4; ++mm) {
      Mrg[w][mm * 16 + lr][0] = m_run[mm];
      Mrg[w][mm * 16 + lr][1] = numden[mm][1];
      Mrg[w][mm * 16 + lr][2] = numden[mm][0];
    }
  }
  __syncthreads();

  if (t < 64) {
    float M = Mrg[0][t][0];
#pragma unroll
    for (int hh = 1; hh < 4; ++hh) M = fmaxf(M, Mrg[hh][t][0]);
    float dt = 0.f, nt = 0.f;
#pragma unroll
    for (int hh = 0; hh < 4; ++hh) {
      const float e = __builtin_amdgcn_exp2f(Mrg[hh][t][0] - M);
      dt += e * Mrg[hh][t][1];
      nt += e * Mrg[hh][t][2];
    }
    const size_t idx = (size_t)half * (BQ * SQ) + (size_t)b * SQ + qbase + t;
    Pm[idx] = M; Pd[idx] = dt; Pn[idx] = nt;
  }
#undef STAGE
}

// ---------------- merge the 2 key-halves ----------------
__global__ void merge_kernel(const float* __restrict__ Pm,
                             const float* __restrict__ Pd,
                             const float* __restrict__ Pn,
                             const float* __restrict__ Wc,
                             float* __restrict__ out) {
  const int gid = blockIdx.x * 256 + threadIdx.x;
  const float m0 = Pm[gid], m1 = Pm[BQ * SQ + gid];
  const float M = fmaxf(m0, m1);
  const float e0 = __builtin_amdgcn_exp2f(m0 - M);
  const float e1 = __builtin_amdgcn_exp2f(m1 - M);
  const float den = e0 * Pd[gid] + e1 * Pd[BQ * SQ + gid];
  const float num = e0 * Pn[gid] + e1 * Pn[BQ * SQ + gid];
  out[gid] = num / den + Wc[256];
}

// ---------------- launch ----------------
extern "C" void kernel_launch(void* const* d_in, const int* in_sizes, int n_in,
                              void* d_out, int out_size, void* d_ws, size_t ws_size,
                              hipStream_t stream) {
  const float* x     = (const float*)d_in[0];
  const float* Wqkv  = (const float*)d_in[1];
  const float* bqkv  = (const float*)d_in[2];
  const float* Wproj = (const float*)d_in[3];
  const float* bproj = (const float*)d_in[4];
  const float* Wfc   = (const float*)d_in[5];
  const float* bfc   = (const float*)d_in[6];
  float* out = (float*)d_out;

  const size_t SEG = (size_t)BQ * SQ * DQ * 2;  // 8 MB per fp16 tensor
  char* wsb = (char*)d_ws;
  short* Qb     = (short*)(wsb);
  short* Kb     = (short*)(wsb + SEG);
  short* x16    = (short*)(wsb + 2 * SEG);             // 8 MB fp16 x
  char* base    = wsb + 3 * SEG;
  float* Wc     = (float*)(base);                      // 257 f (pad 2KB)
  short* u16    = (short*)(base + 2048);               // 32 KB
  short* W16T   = (short*)(base + 2048 + 32768);       // 384 KB
  float* u_part = (float*)(base + 2048 + 32768 + 393216);          // 256 KB
  float* Pm     = (float*)(base + 2048 + 32768 + 393216 + 262144); // 128 KB x3
  float* Pd     = Pm + 2 * BQ * SQ;
  float* Pn     = Pd + 2 * BQ * SQ;

  prep_kernel<<<305, 256, 0, stream>>>(Wqkv, Wproj, bproj, Wfc, bfc, x,
                                       W16T, Wc, x16);
  qkv_kernel<<<dim3(128, 12), 512, 0, stream>>>(x16, W16T, bqkv, Wc, Qb, Kb,
                                                u_part);
  uvec_kernel<<<BQ * SQ / 256, 256, 0, stream>>>(u_part, u16);
  attn_kernel<<<512, 256, 0, stream>>>(Qb, Kb, u16, Pm, Pd, Pn);
  merge_kernel<<<BQ * SQ / 256, 256, 0, stream>>>(Pm, Pd, Pn, Wc, out);
}